// Round 1
// baseline (85.906 us; speedup 1.0000x reference)
//
#include <hip/hip_runtime.h>

#define BB   128      // batch
#define TT   4096     // time
#define NSH  257      // shifts -128..+128 -> j = 0..256
#define PAD  128
#define LTOT 4352.0f  // padded length
#define TC   2048     // t-chunk per block (2 chunks per row)
#define PPW  (TC + 256) // pp window floats per chunk

__device__ __forceinline__ float wave_sum(float v) {
    #pragma unroll
    for (int m = 32; m; m >>= 1) v += __shfl_xor(v, m, 64);
    return v;
}

// cov[b][j] partial cross-correlations + per-row stats, via LDS-staged sliding window.
extern "C" __global__ __launch_bounds__(256)
void k_corr(const float* __restrict__ preds, const float* __restrict__ labels,
            float* __restrict__ cov_g, float* __restrict__ stats_g) {
    __shared__ float pp_s[PPW];   // P[t0 + v], P[x] = preds[x-128] zero-padded
    __shared__ float lab_s[TC];
    __shared__ float cov_s[NSH];

    const int bid = blockIdx.x;
    const int b   = bid >> 1;
    const int t0  = (bid & 1) * TC;
    const int tid = threadIdx.x;

    const float* pr = preds  + b * TT;
    const float* lr = labels + b * TT;

    // ---- stage (coalesced) ----
    #pragma unroll
    for (int v = tid; v < PPW; v += 256) {
        int idx = t0 + v - PAD;
        pp_s[v] = (idx >= 0 && idx < TT) ? pr[idx] : 0.0f;
    }
    #pragma unroll
    for (int v = tid; v < TC; v += 256) lab_s[v] = lr[t0 + v];
    for (int j = tid; j < NSH; j += 256) cov_s[j] = 0.0f;
    __syncthreads();

    // ---- main: thread = 4 consecutive shifts (j = 4l..4l+3), wave = t-subchunk ----
    const int l    = tid & 63;       // shift group
    const int wv   = tid >> 6;       // wave id = subchunk
    const int tq0  = wv * (TC / 4);  // 512 t per wave
    const int boff = 256 - 4 * l;

    float4 prev = *reinterpret_cast<const float4*>(&pp_s[tq0 + boff - 4]);
    float a0 = 0.f, a1 = 0.f, a2 = 0.f, a3 = 0.f;

    #pragma unroll 4
    for (int tq = tq0; tq < tq0 + TC / 4; tq += 4) {
        const float4 lab = *reinterpret_cast<const float4*>(&lab_s[tq]);        // broadcast
        const float4 cur = *reinterpret_cast<const float4*>(&pp_s[tq + boff]);  // conflict-free b128
        // acc[k] += lab[tt] * P[base + tt - k], window {prev,cur} = P[base-4 .. base+3]
        a0 += lab.x * cur.x;  a0 += lab.y * cur.y;  a0 += lab.z * cur.z;  a0 += lab.w * cur.w;
        a1 += lab.x * prev.w; a1 += lab.y * cur.x;  a1 += lab.z * cur.y;  a1 += lab.w * cur.z;
        a2 += lab.x * prev.z; a2 += lab.y * prev.w; a2 += lab.z * cur.x;  a2 += lab.w * cur.y;
        a3 += lab.x * prev.y; a3 += lab.y * prev.z; a3 += lab.z * prev.w; a3 += lab.w * cur.x;
        prev = cur;
    }
    atomicAdd(&cov_s[4 * l + 0], a0);
    atomicAdd(&cov_s[4 * l + 1], a1);
    atomicAdd(&cov_s[4 * l + 2], a2);
    atomicAdd(&cov_s[4 * l + 3], a3);

    // ---- shift j=256 (s=+128): sum labels[t]*P[t] ----
    {
        float e = 0.f;
        const int vb = tid * (TC / 256);   // 8 elems/thread
        #pragma unroll
        for (int u = 0; u < TC / 256; ++u) e += lab_s[vb + u] * pp_s[vb + u];
        e = wave_sum(e);
        if (l == 0) atomicAdd(&cov_s[256], e);
    }

    // ---- per-chunk stats ----
    {
        float sp = 0.f, spp = 0.f, sl = 0.f, sll = 0.f;
        #pragma unroll
        for (int v = tid; v < TC; v += 256) {
            float pv = pp_s[v + PAD];   // = preds[t0+v]
            float lv = lab_s[v];
            sp += pv; spp += pv * pv; sl += lv; sll += lv * lv;
        }
        sp = wave_sum(sp); spp = wave_sum(spp); sl = wave_sum(sl); sll = wave_sum(sll);
        if (l == 0) {
            atomicAdd(&stats_g[b * 4 + 0], sp);
            atomicAdd(&stats_g[b * 4 + 1], spp);
            atomicAdd(&stats_g[b * 4 + 2], sl);
            atomicAdd(&stats_g[b * 4 + 3], sll);
        }
    }

    __syncthreads();
    for (int j = tid; j < NSH; j += 256) atomicAdd(&cov_g[b * NSH + j], cov_s[j]);
}

// corr -> max over shifts -> mean over batch
extern "C" __global__ __launch_bounds__(1024)
void k_final(const float* __restrict__ cov_g, const float* __restrict__ stats_g,
             float* __restrict__ out) {
    __shared__ float part[16];
    const int tid  = threadIdx.x;
    const int lane = tid & 63;
    const int wv   = tid >> 6;   // 16 waves

    float sum = 0.f;
    for (int b = wv; b < BB; b += 16) {
        float Sp  = stats_g[b * 4 + 0], Spp = stats_g[b * 4 + 1];
        float Sl  = stats_g[b * 4 + 2], Sll = stats_g[b * 4 + 3];
        float xn2 = Spp - Sp * Sp / LTOT;
        float yn2 = Sll - Sl * Sl / LTOT;
        float inv = rsqrtf(xn2 * yn2);
        float cst = Sp * Sl / LTOT;
        float mx = -1e30f;
        for (int j = lane; j < NSH; j += 64)
            mx = fmaxf(mx, (cov_g[b * NSH + j] - cst) * inv);
        #pragma unroll
        for (int m = 32; m; m >>= 1) mx = fmaxf(mx, __shfl_xor(mx, m, 64));
        sum += 1.0f - mx;
    }
    if (lane == 0) part[wv] = sum;
    __syncthreads();
    if (tid == 0) {
        float t = 0.f;
        #pragma unroll
        for (int w = 0; w < 16; ++w) t += part[w];
        out[0] = t * (1.0f / BB);
    }
}

extern "C" void kernel_launch(void* const* d_in, const int* in_sizes, int n_in,
                              void* d_out, int out_size, void* d_ws, size_t ws_size,
                              hipStream_t stream) {
    const float* preds  = (const float*)d_in[0];
    const float* labels = (const float*)d_in[1];
    float* out     = (float*)d_out;
    float* cov_g   = (float*)d_ws;                 // [128][257]
    float* stats_g = cov_g + BB * NSH;             // [128][4]

    hipMemsetAsync(d_ws, 0, (size_t)(BB * NSH + BB * 4) * sizeof(float), stream);
    hipLaunchKernelGGL(k_corr, dim3(BB * 2), dim3(256), 0, stream,
                       preds, labels, cov_g, stats_g);
    hipLaunchKernelGGL(k_final, dim3(1), dim3(1024), 0, stream,
                       cov_g, stats_g, out);
}